// Round 4
// baseline (2714.924 us; speedup 1.0000x reference)
//
#include <hip/hip_runtime.h>

// Linear RNN: h_0 = initial + proj[0]; h_t = h_{t-1} @ Whh^T + proj[t-1], t=1..T-1
// out = (hidden, hidden) concatenated, hidden[n][t][j] fp32.
//
// R5: R4's phase was grid-capped at 1 block/CU (occ 22.5%, ~14us/step stall).
// NC 256->512 (CK 16->8): 2 co-resident blocks/CU -> stalls of one block hide
// under the other's FMA issue. KS becomes 9 rounds over 512 boundaries (also
// 2 blocks/CU -> ~neutral). Plus: t-invariant W quads prefetched across the
// step barrier (only LDS h-reads on post-barrier critical path), B/out pointers
// strength-reduced (+= HH per step).
// Memory: ws = [G_final 16MB][WhhT 1MB] (read during phase3 which overwrites
// all of out; REQUIRES ws_size >= 17MB). Half-A tail (dead until phase3):
// [tailG 16MB][WiT 0.5][matsT 9][mats 11]. No dispatch-order assumptions.
// Ascending-k fmaf order unchanged -> numerics identical to R4.

constexpr int NN = 16;
constexpr int TT = 4096;
constexpr int II = 256;
constexpr int HH = 512;
constexpr int CK = 8;                  // steps per chunk
constexpr int NC = 512;                // chunks
constexpr long NTH = (long)NN * TT * HH;   // floats per output half
constexpr int NMATS = 11;              // W^2 .. W^2048
constexpr int NKS = 9;                 // KS rounds (log2 NC)

__device__ __forceinline__ float4 ld4(const float* p) { return *(const float4*)p; }

// acc0..acc3 are float4 (4 cols) for 4 rows; e0..e3 are the rows' k-elements.
#define FMA16(W_, e0, e1, e2, e3) \
    acc0.x = fmaf(e0, (W_).x, acc0.x); acc0.y = fmaf(e0, (W_).y, acc0.y); \
    acc0.z = fmaf(e0, (W_).z, acc0.z); acc0.w = fmaf(e0, (W_).w, acc0.w); \
    acc1.x = fmaf(e1, (W_).x, acc1.x); acc1.y = fmaf(e1, (W_).y, acc1.y); \
    acc1.z = fmaf(e1, (W_).z, acc1.z); acc1.w = fmaf(e1, (W_).w, acc1.w); \
    acc2.x = fmaf(e2, (W_).x, acc2.x); acc2.y = fmaf(e2, (W_).y, acc2.y); \
    acc2.z = fmaf(e2, (W_).z, acc2.z); acc2.w = fmaf(e2, (W_).w, acc2.w); \
    acc3.x = fmaf(e3, (W_).x, acc3.x); acc3.y = fmaf(e3, (W_).y, acc3.y); \
    acc3.z = fmaf(e3, (W_).z, acc3.z); acc3.w = fmaf(e3, (W_).w, acc3.w);

// one k-quad: W rows k..k+3 (cols j..j+3), h rows n0..n0+3 (elems k..k+3)
#define COMPUTE(sl) \
    FMA16(wv##sl[0], hv##sl[0].x, hv##sl[1].x, hv##sl[2].x, hv##sl[3].x) \
    FMA16(wv##sl[1], hv##sl[0].y, hv##sl[1].y, hv##sl[2].y, hv##sl[3].y) \
    FMA16(wv##sl[2], hv##sl[0].z, hv##sl[1].z, hv##sl[2].z, hv##sl[3].z) \
    FMA16(wv##sl[3], hv##sl[0].w, hv##sl[1].w, hv##sl[2].w, hv##sl[3].w)

// prefetch quad kk: W part (global, t-invariant) and h part (LDS, per-step)
#define PRE_W(sl, kk) { \
    const float* wp_ = WT + (size_t)(4 * (kk)) * HH + j; \
    wv##sl[0] = ld4(wp_);            wv##sl[1] = ld4(wp_ + HH); \
    wv##sl[2] = ld4(wp_ + 2 * HH);   wv##sl[3] = ld4(wp_ + 3 * HH); }
#define PRE_H(sl, kk) { \
    hv##sl[0] = hs[hb0 + (((kk)) ^ sw0)]; hv##sl[1] = hs[hb1 + (((kk)) ^ sw0)]; \
    hv##sl[2] = hs[hb2 + (((kk)) ^ sw1)]; hv##sl[3] = hs[hb3 + (((kk)) ^ sw1)]; }
#define PRE_PH(sl, kk) { PRE_W(sl, kk) PRE_H(sl, kk) }

#define PIPE_DECL float4 wv0[4], wv1[4], wv2[4], wv3[4]; \
                  float4 hv0[4], hv1[4], hv2[4], hv3[4];

// ----------------------------------------------------------- transpose ------
// dst[C][R] = src[R][C]^T for blockIdx.z-th matrix. grid (C/32, R/32, nz).
__global__ __launch_bounds__(256) void trg_kernel(
    const float* __restrict__ src, float* __restrict__ dst, int R, int C)
{
    __shared__ float tile[32][33];
    const size_t mo = (size_t)blockIdx.z * R * C;
    const int x0 = blockIdx.x * 32, y0 = blockIdx.y * 32;
    const int tx = threadIdx.x & 31, ty = threadIdx.x >> 5;
#pragma unroll
    for (int r = 0; r < 4; r++)
        tile[ty + 8 * r][tx] = src[mo + (size_t)(y0 + ty + 8 * r) * C + (x0 + tx)];
    __syncthreads();
#pragma unroll
    for (int r = 0; r < 4; r++)
        dst[mo + (size_t)(x0 + ty + 8 * r) * R + (y0 + tx)] = tile[tx][ty + 8 * r];
}

// ---------------------------------------------------------------- proj ------
// B[n][t][j] = bi[j] + sum_i x[n][max(t-1,0)][i] * WiT[i][j]
// grid (TT/32, HH/128, NN), block 256. Thread: 4 t-rows x 4 j-cols.
__global__ __launch_bounds__(256) void proj_kernel(
    const float* __restrict__ x, const float* __restrict__ WiT,
    const float* __restrict__ bi, float* __restrict__ Bh)
{
    const int t0 = blockIdx.x * 32;
    const int j0 = blockIdx.y * 128;
    const int n  = blockIdx.z;
    // swizzled: x[t][i-quad q] at slot t*64 + (q ^ (t>>2)). 32 KB.
    __shared__ float4 xs[32 * 64];

    {   // stage 32 x-rows (with t-1 shift, clamped)
        const int r  = threadIdx.x >> 3;
        const int ci = threadIdx.x & 7;
        int s = t0 + r - 1; if (s < 0) s = 0;
        const float4* src = (const float4*)(x + ((size_t)n * TT + s) * II);
        const int rb = r * 64, rs = r >> 2;
#pragma unroll
        for (int q = 0; q < 8; q++) xs[rb + ((ci + 8 * q) ^ rs)] = src[ci + 8 * q];
    }
    __syncthreads();

    const int tj  = threadIdx.x & 31;
    const int tt4 = threadIdx.x >> 5;   // 0..7
    const int j   = j0 + tj * 4;
    const int xb0 = (tt4 * 4 + 0) * 64, xb1 = (tt4 * 4 + 1) * 64;
    const int xb2 = (tt4 * 4 + 2) * 64, xb3 = (tt4 * 4 + 3) * 64;
    const int swx = tt4;

    float4 acc0 = {0,0,0,0}, acc1 = {0,0,0,0}, acc2 = {0,0,0,0}, acc3 = {0,0,0,0};
    PIPE_DECL
#define PRE_PJ(sl, kk) { \
    const float* wp_ = WiT + (size_t)(4 * (kk)) * HH + j; \
    wv##sl[0] = ld4(wp_);            wv##sl[1] = ld4(wp_ + HH); \
    wv##sl[2] = ld4(wp_ + 2 * HH);   wv##sl[3] = ld4(wp_ + 3 * HH); \
    hv##sl[0] = xs[xb0 + (((kk)) ^ swx)]; hv##sl[1] = xs[xb1 + (((kk)) ^ swx)]; \
    hv##sl[2] = xs[xb2 + (((kk)) ^ swx)]; hv##sl[3] = xs[xb3 + (((kk)) ^ swx)]; }

    PRE_PJ(0, 0) PRE_PJ(1, 1) PRE_PJ(2, 2) PRE_PJ(3, 3)
    for (int g = 0; g < 15; g++) {          // kq = 4g .. 4g+3, computes 0..59
        const int kq = g * 4;
        COMPUTE(0) PRE_PJ(0, kq + 4)
        COMPUTE(1) PRE_PJ(1, kq + 5)
        COMPUTE(2) PRE_PJ(2, kq + 6)
        COMPUTE(3) PRE_PJ(3, kq + 7)
    }
    COMPUTE(0) COMPUTE(1) COMPUTE(2) COMPUTE(3)   // kq = 60..63

    const float4 bv = ld4(bi + j);
    {
        const int tb = t0 + tt4 * 4;
        *(float4*)(Bh + ((size_t)n * TT + tb + 0) * HH + j) =
            make_float4(acc0.x + bv.x, acc0.y + bv.y, acc0.z + bv.z, acc0.w + bv.w);
        *(float4*)(Bh + ((size_t)n * TT + tb + 1) * HH + j) =
            make_float4(acc1.x + bv.x, acc1.y + bv.y, acc1.z + bv.z, acc1.w + bv.w);
        *(float4*)(Bh + ((size_t)n * TT + tb + 2) * HH + j) =
            make_float4(acc2.x + bv.x, acc2.y + bv.y, acc2.z + bv.z, acc2.w + bv.w);
        *(float4*)(Bh + ((size_t)n * TT + tb + 3) * HH + j) =
            make_float4(acc3.x + bv.x, acc3.y + bv.y, acc3.z + bv.z, acc3.w + bv.w);
    }
}

// ---------------------------------------------------------- phase 1 / 3 -----
// One block/chunk, 512 threads: thread = (nq=tid&3 -> 4 rows, jq=tid>>2 -> 4 cols).
// h in swizzled LDS: h[n] quad kq at slot n*128 + (kq ^ (n>>1)).
// NC=512 -> 2 blocks/CU; W quads prefetched across the step barrier.
template <int PHASE>
__global__ __launch_bounds__(512, 2) void phase_kernel(
    const float* __restrict__ WT,     // Whh^T [k][j]
    float* __restrict__ Bh,           // half B (phase3 overwrites with h)
    const float* __restrict__ init_,  // initial [N][H]
    const float* __restrict__ Gin,    // boundary states [NC][N][H]
    float* __restrict__ Zout,         // chunk-final local states [NC][N][H]
    float* __restrict__ outA)         // half A
{
    __shared__ float4 hs[NN * 128];   // 32 KB
    const int c   = blockIdx.x;
    const int tid = threadIdx.x;
    const int nq  = tid & 3;
    const int n0  = nq * 4;
    const int jq  = tid >> 2;         // 0..127
    const int j   = jq * 4;
    const int hb0 = (n0 + 0) * 128, hb1 = (n0 + 1) * 128;
    const int hb2 = (n0 + 2) * 128, hb3 = (n0 + 3) * 128;
    const int sw0 = nq * 2, sw1 = nq * 2 + 1;

    {   // stage initial state: 4 rows x 1 float4
        float4 v[4];
        if (c == 0) {
#pragma unroll
            for (int rr = 0; rr < 4; rr++) {
                const int nn = n0 + rr;
                float4 iv = ld4(init_ + (size_t)nn * HH + j);
                float4 bv = ld4(Bh + (size_t)nn * TT * HH + j);
                v[rr] = make_float4(iv.x + bv.x, iv.y + bv.y, iv.z + bv.z, iv.w + bv.w);
                if (PHASE == 3) {
                    *(float4*)(outA + (size_t)nn * TT * HH + j) = v[rr];
                    *(float4*)(Bh   + (size_t)nn * TT * HH + j) = v[rr];
                }
            }
        } else if (PHASE == 1) {
            const int t0 = c * CK;
#pragma unroll
            for (int rr = 0; rr < 4; rr++)
                v[rr] = ld4(Bh + ((size_t)(n0 + rr) * TT + t0) * HH + j);
        } else {
#pragma unroll
            for (int rr = 0; rr < 4; rr++)
                v[rr] = ld4(Gin + (size_t)(c - 1) * NN * HH + (size_t)(n0 + rr) * HH + j);
        }
        hs[hb0 + (jq ^ sw0)] = v[0];
        hs[hb1 + (jq ^ sw0)] = v[1];
        hs[hb2 + (jq ^ sw1)] = v[2];
        hs[hb3 + (jq ^ sw1)] = v[3];
    }
    __syncthreads();

    // PHASE 1: init value IS the local state at t0 -> loop from t0+1.
    // PHASE 3: init value is the state at t0-1 (true boundary) -> loop from t0.
    const int tstart = (PHASE == 1) ? (c * CK + 1) : ((c == 0) ? 1 : c * CK);
    const int tend   = c * CK + CK;

    // strength-reduced row pointers (advance by HH per step)
    float* bp0 = Bh + ((size_t)(n0 + 0) * TT + tstart) * HH + j;
    float* bp1 = Bh + ((size_t)(n0 + 1) * TT + tstart) * HH + j;
    float* bp2 = Bh + ((size_t)(n0 + 2) * TT + tstart) * HH + j;
    float* bp3 = Bh + ((size_t)(n0 + 3) * TT + tstart) * HH + j;
    float* op0 = outA + ((size_t)(n0 + 0) * TT + tstart) * HH + j;
    float* op1 = outA + ((size_t)(n0 + 1) * TT + tstart) * HH + j;
    float* op2 = outA + ((size_t)(n0 + 2) * TT + tstart) * HH + j;
    float* op3 = outA + ((size_t)(n0 + 3) * TT + tstart) * HH + j;

    PIPE_DECL
    PRE_W(0, 0) PRE_W(1, 1) PRE_W(2, 2) PRE_W(3, 3)   // W is t-invariant

    for (int t = tstart; t < tend; t++) {
        // issue B addends early: latency hides under the k-loop
        float4 b0 = ld4(bp0), b1 = ld4(bp1), b2 = ld4(bp2), b3 = ld4(bp3);

        float4 acc0 = {0,0,0,0}, acc1 = {0,0,0,0}, acc2 = {0,0,0,0}, acc3 = {0,0,0,0};
        PRE_H(0, 0) PRE_H(1, 1) PRE_H(2, 2) PRE_H(3, 3)
        for (int g = 0; g < 31; g++) {      // computes kq 0..123, prefetch 4..127
            const int kq = g * 4;
            COMPUTE(0) PRE_PH(0, kq + 4)
            COMPUTE(1) PRE_PH(1, kq + 5)
            COMPUTE(2) PRE_PH(2, kq + 6)
            COMPUTE(3) PRE_PH(3, kq + 7)
        }
        // kq = 124..127; refill W quads 0..3 for the NEXT step across the barrier
        COMPUTE(0) PRE_W(0, 0)
        COMPUTE(1) PRE_W(1, 1)
        COMPUTE(2) PRE_W(2, 2)
        COMPUTE(3) PRE_W(3, 3)

        float4 o0 = make_float4(acc0.x + b0.x, acc0.y + b0.y, acc0.z + b0.z, acc0.w + b0.w);
        float4 o1 = make_float4(acc1.x + b1.x, acc1.y + b1.y, acc1.z + b1.z, acc1.w + b1.w);
        float4 o2 = make_float4(acc2.x + b2.x, acc2.y + b2.y, acc2.z + b2.z, acc2.w + b2.w);
        float4 o3 = make_float4(acc3.x + b3.x, acc3.y + b3.y, acc3.z + b3.z, acc3.w + b3.w);

        __syncthreads();   // all reads of hs done
        hs[hb0 + (jq ^ sw0)] = o0;
        hs[hb1 + (jq ^ sw0)] = o1;
        hs[hb2 + (jq ^ sw1)] = o2;
        hs[hb3 + (jq ^ sw1)] = o3;
        if (PHASE == 3) {
            *(float4*)op0 = o0; *(float4*)op1 = o1;
            *(float4*)op2 = o2; *(float4*)op3 = o3;
            *(float4*)bp0 = o0; *(float4*)bp1 = o1;
            *(float4*)bp2 = o2; *(float4*)bp3 = o3;
            op0 += HH; op1 += HH; op2 += HH; op3 += HH;
        }
        bp0 += HH; bp1 += HH; bp2 += HH; bp3 += HH;
        __syncthreads();   // writes visible before next step's reads
    }

    if (PHASE == 1) {
        float* zp = Zout + (size_t)c * NN * HH;
        *(float4*)(zp + (size_t)(n0 + 0) * HH + j) = hs[hb0 + (jq ^ sw0)];
        *(float4*)(zp + (size_t)(n0 + 1) * HH + j) = hs[hb1 + (jq ^ sw0)];
        *(float4*)(zp + (size_t)(n0 + 2) * HH + j) = hs[hb2 + (jq ^ sw1)];
        *(float4*)(zp + (size_t)(n0 + 3) * HH + j) = hs[hb3 + (jq ^ sw1)];
    }
}

// ----------------------------------------------------------- squaring -------
// Out = A @ A, 512x512 row-major. grid (4, 32). Thread: 4 rows x 2 cols, pipelined.
__global__ __launch_bounds__(256) void sq_kernel(
    const float* __restrict__ A, float* __restrict__ Out)
{
    const int j0 = blockIdx.x * 128;
    const int a0 = blockIdx.y * 16;
    // swizzled: A[a0+r] quad q at slot r*128 + (q ^ (r>>2)). 32 KB.
    __shared__ float4 As[16 * 128];
    {
#pragma unroll
        for (int rr = 0; rr < 8; rr++) {
            int idx = threadIdx.x + rr * 256;      // 0..2047
            int row = idx >> 7, s = idx & 127;
            As[row * 128 + (s ^ (row >> 2))] = ld4(A + (size_t)(a0 + row) * HH + s * 4);
        }
    }
    __syncthreads();

    const int jh = threadIdx.x & 63;
    const int j  = j0 + jh * 2;
    const int rq = threadIdx.x >> 6;      // 0..3 (uniform per wave -> As broadcast)
    const int ab0 = (rq * 4 + 0) * 128, ab1 = (rq * 4 + 1) * 128;
    const int ab2 = (rq * 4 + 2) * 128, ab3 = (rq * 4 + 3) * 128;

    float2 bw0[4], bw1[4], bw2[4], bw3[4];
    float4 av0[4], av1[4], av2[4], av3[4];
    float2 c0 = {0,0}, c1 = {0,0}, c2 = {0,0}, c3 = {0,0};
#define SQ_PRE(sl, kk) { \
    const float* bp_ = A + (size_t)(4 * (kk)) * HH + j; \
    bw##sl[0] = *(const float2*)(bp_);            bw##sl[1] = *(const float2*)(bp_ + HH); \
    bw##sl[2] = *(const float2*)(bp_ + 2 * HH);   bw##sl[3] = *(const float2*)(bp_ + 3 * HH); \
    av##sl[0] = As[ab0 + (((kk)) ^ rq)]; av##sl[1] = As[ab1 + (((kk)) ^ rq)]; \
    av##sl[2] = As[ab2 + (((kk)) ^ rq)]; av##sl[3] = As[ab3 + (((kk)) ^ rq)]; }
#define SQ_F(Bv_, e0, e1, e2, e3) \
    c0.x = fmaf(e0, (Bv_).x, c0.x); c0.y = fmaf(e0, (Bv_).y, c0.y); \
    c1.x = fmaf(e1, (Bv_).x, c1.x); c1.y = fmaf(e1, (Bv_).y, c1.y); \
    c2.x = fmaf(e2, (Bv_).x, c2.x); c2.y = fmaf(e2, (Bv_).y, c2.y); \
    c3.x = fmaf(e3, (Bv_).x, c3.x); c3.y = fmaf(e3, (Bv_).y, c3.y);
#define SQ_C(sl) \
    SQ_F(bw##sl[0], av##sl[0].x, av##sl[1].x, av##sl[2].x, av##sl[3].x) \
    SQ_F(bw##sl[1], av##sl[0].y, av##sl[1].y, av##sl[2].y, av##sl[3].y) \
    SQ_F(bw##sl[2], av##sl[0].z, av##sl[1].z, av##sl[2].z, av##sl[3].z) \
    SQ_F(bw##sl[3], av##sl[0].w, av##sl[1].w, av##sl[2].w, av##sl[3].w)

    SQ_PRE(0, 0) SQ_PRE(1, 1) SQ_PRE(2, 2) SQ_PRE(3, 3)
    for (int g = 0; g < 31; g++) {
        const int kq = g * 4;
        SQ_C(0) SQ_PRE(0, kq + 4)
        SQ_C(1) SQ_PRE(1, kq + 5)
        SQ_C(2) SQ_PRE(2, kq + 6)
        SQ_C(3) SQ_PRE(3, kq + 7)
    }
    SQ_C(0) SQ_C(1) SQ_C(2) SQ_C(3)

    *(float2*)(Out + (size_t)(a0 + rq * 4 + 0) * HH + j) = c0;
    *(float2*)(Out + (size_t)(a0 + rq * 4 + 1) * HH + j) = c1;
    *(float2*)(Out + (size_t)(a0 + rq * 4 + 2) * HH + j) = c2;
    *(float2*)(Out + (size_t)(a0 + rq * 4 + 3) * HH + j) = c3;
}

// --------------------------------------------------------- Kogge-Stone ------
// Gout[c] = Gin[c] + Gin[c-s] @ P^T (WT = transposed power), copy for c < s.
// grid (NC), block 512: same tile/pipeline as phase step.
__global__ __launch_bounds__(512, 2) void ks_kernel(
    const float* __restrict__ Gin, float* __restrict__ Gout,
    const float* __restrict__ WT, int sft)
{
    __shared__ float4 hs[NN * 128];
    const int c   = blockIdx.x;
    const int tid = threadIdx.x;

    if (c < sft) {   // copy
        const float4* src = (const float4*)(Gin + (size_t)c * NN * HH);
        float4* dst = (float4*)(Gout + (size_t)c * NN * HH);
#pragma unroll
        for (int r = 0; r < 4; r++) dst[tid + r * 512] = src[tid + r * 512];
        return;
    }

    const int nq  = tid & 3;
    const int n0  = nq * 4;
    const int jq  = tid >> 2;
    const int j   = jq * 4;
    const int hb0 = (n0 + 0) * 128, hb1 = (n0 + 1) * 128;
    const int hb2 = (n0 + 2) * 128, hb3 = (n0 + 3) * 128;
    const int sw0 = nq * 2, sw1 = nq * 2 + 1;

    float4 g[4];
    {
        const float* sp = Gin + (size_t)(c - sft) * NN * HH;
        const float* gp = Gin + (size_t)c * NN * HH;
        float4 v[4];
#pragma unroll
        for (int rr = 0; rr < 4; rr++) {
            v[rr] = ld4(sp + (size_t)(n0 + rr) * HH + j);
            g[rr] = ld4(gp + (size_t)(n0 + rr) * HH + j);
        }
        hs[hb0 + (jq ^ sw0)] = v[0];
        hs[hb1 + (jq ^ sw0)] = v[1];
        hs[hb2 + (jq ^ sw1)] = v[2];
        hs[hb3 + (jq ^ sw1)] = v[3];
    }
    __syncthreads();

    float4 acc0 = {0,0,0,0}, acc1 = {0,0,0,0}, acc2 = {0,0,0,0}, acc3 = {0,0,0,0};
    PIPE_DECL
    PRE_PH(0, 0) PRE_PH(1, 1) PRE_PH(2, 2) PRE_PH(3, 3)
    for (int g2 = 0; g2 < 31; g2++) {
        const int kq = g2 * 4;
        COMPUTE(0) PRE_PH(0, kq + 4)
        COMPUTE(1) PRE_PH(1, kq + 5)
        COMPUTE(2) PRE_PH(2, kq + 6)
        COMPUTE(3) PRE_PH(3, kq + 7)
    }
    COMPUTE(0) COMPUTE(1) COMPUTE(2) COMPUTE(3)

    float* op = Gout + (size_t)c * NN * HH;
    *(float4*)(op + (size_t)(n0 + 0) * HH + j) =
        make_float4(g[0].x + acc0.x, g[0].y + acc0.y, g[0].z + acc0.z, g[0].w + acc0.w);
    *(float4*)(op + (size_t)(n0 + 1) * HH + j) =
        make_float4(g[1].x + acc1.x, g[1].y + acc1.y, g[1].z + acc1.z, g[1].w + acc1.w);
    *(float4*)(op + (size_t)(n0 + 2) * HH + j) =
        make_float4(g[2].x + acc2.x, g[2].y + acc2.y, g[2].z + acc2.z, g[2].w + acc2.w);
    *(float4*)(op + (size_t)(n0 + 3) * HH + j) =
        make_float4(g[3].x + acc3.x, g[3].y + acc3.y, g[3].z + acc3.z, g[3].w + acc3.w);
}

// ------------------------------------------------------------- launch -------
extern "C" void kernel_launch(void* const* d_in, const int* in_sizes, int n_in,
                              void* d_out, int out_size, void* d_ws, size_t ws_size,
                              hipStream_t stream)
{
    const float* x    = (const float*)d_in[0];
    const float* ini  = (const float*)d_in[1];
    const float* Wi   = (const float*)d_in[2];
    const float* bi   = (const float*)d_in[3];
    const float* Whh  = (const float*)d_in[4];
    float* out   = (float*)d_out;
    float* halfB = out + NTH;

    // Half-A tail scratch (all reads complete before phase3's writes reach it):
    // [tailG 16MB][WiT 0.5MB][matsT 9MB][mats 11MB]
    float* mats  = out + NTH - (long)NMATS * HH * HH;
    float* matsT = mats - (long)NKS * HH * HH;
    float* WiT   = matsT - (long)II * HH;
    float* tailG = WiT - (long)NC * NN * HH;

    // Workspace (read DURING phase3, must be outside out): [G_final][WhhT]
    // requires ws_size >= (NC*NN*HH + HH*HH) * 4 = 17 MB.
    float* wsG  = (float*)d_ws;
    float* wsWT = wsG + (size_t)NC * NN * HH;

    // 0) transposes: WiT (tail), WhhT (ws, used by both phases)
    trg_kernel<<<dim3(II / 32, HH / 32, 1), 256, 0, stream>>>(Wi, WiT, HH, II);
    trg_kernel<<<dim3(16, 16, 1), 256, 0, stream>>>(Whh, wsWT, HH, HH);

    // 0b) shifted input projection -> half B
    proj_kernel<<<dim3(TT / 32, HH / 128, NN), 256, 0, stream>>>(x, WiT, bi, halfB);

    // 1) chunk-local scans -> z_c in tailG
    phase_kernel<1><<<dim3(NC), 512, 0, stream>>>(wsWT, halfB, ini, nullptr, tailG, nullptr);

    // 2) powers W^2 .. W^2048
    sq_kernel<<<dim3(4, 32), 256, 0, stream>>>(Whh, mats);
    for (int i = 1; i < NMATS; i++)
        sq_kernel<<<dim3(4, 32), 256, 0, stream>>>(mats + (size_t)(i - 1) * HH * HH,
                                                   mats + (size_t)i * HH * HH);
    // 2b) transposed powers W^8 .. W^2048 (mats[2..10] -> matsT[0..8])
    trg_kernel<<<dim3(16, 16, NKS), 256, 0, stream>>>(mats + (size_t)2 * HH * HH, matsT,
                                                      HH, HH);

    // 3) Kogge-Stone over 512 boundary states (round r uses (W^(8*2^r))^T)
    //    even r: tailG -> wsG; odd r: wsG -> tailG. 9 rounds -> final in wsG.
    for (int r = 0; r < NKS; r++) {
        const float* src = (r & 1) ? wsG : tailG;
        float* dst       = (r & 1) ? tailG : wsG;
        ks_kernel<<<dim3(NC), 512, 0, stream>>>(src, dst,
                                                matsT + (size_t)r * HH * HH, 1 << r);
    }

    // 4) chunk re-scan from true boundaries (wsG), write both halves
    phase_kernel<3><<<dim3(NC), 512, 0, stream>>>(wsWT, halfB, ini, wsG, nullptr, out);
}